// Round 11
// baseline (173.005 us; speedup 1.0000x reference)
//
#include <hip/hip_runtime.h>

// Adaptive separable conv (SepConv): out[b,c,y,x] = sum_i sum_j inp[b,c,y+i,x+j]*v[b,i,y,x]*h[b,j,y,x]
// B=2,C=3,H=W=256,K=51. fp32 in/out. No MFMA path (per-pixel weights; no fp32 MFMA on CDNA4).
//
// R11: h split LDS/register with COUNTED sync (R9's idea + R9's bug fixed).
// Model (R7 counters): LDS pipe ~75% busy = the wall; h-reads are 52% of LDS bytes and 4x
// wave-redundant. Split: per 4-tap chunk, taps {0,1} staged to LDS via global_load_lds
// (2-tap 4KB chunks, double-buffered, shared by all 4 waves); taps {2,3} per-wave direct
// global->reg (hr[4]), prefetched in-place one chunk ahead. R9 failed because __syncthreads'
// implied vmcnt(0) drained the hr loads every step; here each step ends with
//   s_waitcnt vmcnt(4); s_barrier
// which retires exactly the 1 stage-DMA (issued FIRST in the step, order pinned by
// sched_barrier(0)) and leaves the 4 hr loads in flight across the barrier (full-step
// latency cover). Inactive waves run the same stage/hr/wait sequence -> uniform counts,
// and every wave drains its own DMA before the barrier (no cross-wave race).
// LDS traffic: 2590 -> ~1930 wave-b128/block (-26%); ~650MB h moves to idle VMEM/L2 pipe.
// Keeps R7: R=8, TILE 64x8, 3-slot zero-mov windows, h row-rotation DMA layout,
// 1.25 ops/MAC, NS=4 i-split 4/3/3/3, launch_bounds(256,1). LDS 35.1KB.

namespace {
constexpr int KK = 51;
constexpr int NB = 2;
constexpr int NC = 3;
constexpr int HH = 256;
constexpr int WW = 256;
constexpr int IN_H = HH + KK - 1;   // 306
constexpr int IN_W = WW + KK - 1;   // 306

constexpr int TILE_W = 64;          // output cols per block
constexpr int TILE_H = 8;           // output rows per block
constexpr int NTX = 8;              // threads along x (each covers R=8 outputs)
constexpr int R = 8;
constexpr int NTY = 8;
constexpr int NS = 4;               // i-tap split (one block-range per wave)
constexpr int NTHREADS = NTX * NTY * NS;   // 256
constexpr int HALO_W = TILE_W + KK - 1;    // 114
constexpr int LDS_W = 116;          // 114 valid + 2 slack
constexpr int LDS_H = TILE_H + KK - 1;     // 58
constexpr int KSTRIDE = HH * WW;    // per-tap stride in v/h (65536)
constexpr int HCH = 2 * TILE_H * TILE_W;   // 1024 floats per 2-tap h chunk buffer
}

__device__ __forceinline__ float fget(const float4 v, int i) {
  return (i == 0) ? v.x : (i == 1) ? v.y : (i == 2) ? v.z : v.w;
}

// One j-tap: t = sum_ib v[ib]*w[ib], acc += h*t. P = window phase, JJ = j within chunk.
template <int P, int JJ>
__device__ __forceinline__ void fma_jtap(const float4 (&v4)[4][2], const float4 (&w4)[4][3],
                                         const float4 ha, const float4 hb, float (&acc)[R]) {
#pragma unroll
  for (int rx = 0; rx < R; ++rx) {
    const int k  = rx + JJ;            // logical window index 0..10
    const int sl = (P + k / 4) % 3;    // physical slot
    const int cp = k & 3;
    const int vh = rx >> 2, vc = rx & 3;
    float tv = fget(v4[0][vh], vc) * fget(w4[0][sl], cp);
    tv = fmaf(fget(v4[1][vh], vc), fget(w4[1][sl], cp), tv);
    tv = fmaf(fget(v4[2][vh], vc), fget(w4[2][sl], cp), tv);
    tv = fmaf(fget(v4[3][vh], vc), fget(w4[3][sl], cp), tv);
    const float hv = (rx < 4) ? fget(ha, vc) : fget(hb, vc);
    acc[rx] = fmaf(hv, tv, acc[rx]);
  }
}

// Register part of a chunk: taps jj=2,3 from hr (loaded last step).
template <int P>
__device__ __forceinline__ void reg_part(const float4 (&v4)[4][2], const float4 (&w4)[4][3],
                                         const float4 (&hr)[4], float (&acc)[R]) {
  fma_jtap<P, 2>(v4, w4, hr[0], hr[1], acc);
  fma_jtap<P, 3>(v4, w4, hr[2], hr[3], acc);
}

// LDS part of a chunk: taps jj=0,1 from the staged h buffer; then refill window slot P.
template <int P>
__device__ __forceinline__ void lds_part(const float4 (&v4)[4][2], float4 (&w4)[4][3],
                                         const int (&woff)[4], int wcol,
                                         const float* hb, int off0, int off1,
                                         float (&acc)[R], const float* smem) {
  const float4 h0a = *reinterpret_cast<const float4*>(hb + off0);
  const float4 h0b = *reinterpret_cast<const float4*>(hb + off1);
  const float4 h1a = *reinterpret_cast<const float4*>(hb + 512 + off0);
  const float4 h1b = *reinterpret_cast<const float4*>(hb + 512 + off1);
  fma_jtap<P, 0>(v4, w4, h0a, h0b, acc);
  fma_jtap<P, 1>(v4, w4, h1a, h1b, acc);
#pragma unroll
  for (int ib = 0; ib < 4; ++ib)
    w4[ib][P] = *reinterpret_cast<const float4*>(&smem[woff[ib] + wcol]);
}

__global__ __launch_bounds__(NTHREADS, 1)
void sepconv_kernel(
    const float* __restrict__ inp,
    const float* __restrict__ vert,
    const float* __restrict__ horiz,
    float* __restrict__ out)
{
  __shared__ float lds[LDS_H * LDS_W];   // 26,912 B (inp tile; reused for reduction)
  __shared__ float hbuf[2 * HCH];        // 8,192 B (h taps {0,1} double buffer)

  const int tid = threadIdx.x;
  const int tx  = tid & (NTX - 1);
  const int ty  = (tid >> 3) & (NTY - 1);
  const int s   = tid >> 6;                    // wave id: 0..3 (wave-uniform)

  const int x0 = blockIdx.x * TILE_W;
  const int y0 = blockIdx.y * TILE_H;
  const int bc = blockIdx.z;                   // 0..5
  const int b  = bc / NC;
  const int c  = bc % NC;

  // ---- Stage input tile: 1ch x 58 rows x 114 cols (float2). Cols 114-115 untouched.
  {
    const float* src = inp + (((size_t)(b * NC + c)) * IN_H + y0) * IN_W + x0;
    constexpr int total2 = LDS_H * (HALO_W / 2);   // 58*57 = 3306
    for (int e = tid; e < total2; e += NTHREADS) {
      const int col2 = e % (HALO_W / 2);
      const int r    = e / (HALO_W / 2);
      const float2 v = *reinterpret_cast<const float2*>(src + (size_t)r * IN_W + col2 * 2);
      float* dst = &lds[r * LDS_W + col2 * 2];
      dst[0] = v.x; dst[1] = v.y;
    }
  }

  // ---- h DMA mapping (1 float4/thread/chunk; chunk = taps {0,1}). Physical slot p = tid:
  // jj=p>>7 (0..1), row=(p&127)>>4, c4=p&15; slot holds global quad q=(c4-row)&15
  // (per-row rotation so the b128 read hits the 8-touch/bank floor).
  const float* hblk = horiz + (((size_t)b * KK) * HH + y0) * WW + x0;
  const int jj_  = tid >> 7;
  const int rem  = tid & 127;
  const int hrow = rem >> 4;
  const int c4_  = rem & 15;
  const int q_   = (c4_ - hrow) & 15;
  const int goff = hrow * WW + q_ * 4;
  const int ldso = (tid & ~63) * 4;            // wave-uniform DMA dest base (floats)
  auto stage = [&](int cc, int bufn) {
    const int j = 4 * cc + jj_;                // <= 49, always valid
    const float* g = hblk + (size_t)j * KSTRIDE + goff;
    float* l = &hbuf[bufn * HCH + ldso];
    __builtin_amdgcn_global_load_lds((const __attribute__((address_space(1))) void*)g,
                                     (__attribute__((address_space(3))) void*)l, 16, 0, 0);
  };

  const int lx = tx * R;                 // local LDS col base (32B aligned)
  const int xg = x0 + lx;
  const int yg = y0 + ty;
  const float* hbase = horiz + (((size_t)b * KK) * HH + yg) * WW + xg;

  // Prologue: chunk-0 taps {0,1} -> DMA buf0; chunk-0 taps {2,3} -> registers.
  stage(0, 0);
  float4 hr[4];
  hr[0] = *reinterpret_cast<const float4*>(hbase + (size_t)2 * KSTRIDE);
  hr[1] = *reinterpret_cast<const float4*>(hbase + (size_t)2 * KSTRIDE + 4);
  hr[2] = *reinterpret_cast<const float4*>(hbase + (size_t)3 * KSTRIDE);
  hr[3] = *reinterpret_cast<const float4*>(hbase + (size_t)3 * KSTRIDE + 4);
  __syncthreads();      // full drain once: inp staging + chunk-0 DMA + hr(0)
  int buf = 0;

  // Rotated h read offsets (invariant): row ty, logical quads 2tx, 2tx+1.
  const int off0 = ty * 64 + ((2 * tx + ty) & 15) * 4;
  const int off1 = ty * 64 + ((2 * tx + 1 + ty) & 15) * 4;

  float acc[R];
#pragma unroll
  for (int rx = 0; rx < R; ++rx) acc[rx] = 0.f;

  // Deal 13 BI=4 tap-blocks (52 virtual taps; tap 51 masked) to 4 waves: 4/3/3/3.
  const int blk0 = (s == 0) ? 0 : (3 * s + 1);   // 0,4,7,10
  const int nblk = (s == 0) ? 4 : 3;

  const float* vbase = vert + (((size_t)b * KK) * HH + yg) * WW + xg;

// Step for chunk N (phase PP): stage DMA(N+1) FIRST (pinned oldest), consume hr(N),
// prefetch hr(N+1) in place, compute LDS half, then vmcnt(4)+s_barrier: retires exactly
// the 1 DMA, leaves the 4 hr loads in flight across the barrier.
#define STEP(PP, N, WCOL)                                                        \
  {                                                                              \
    stage((N) + 1, buf ^ 1);                                                     \
    __builtin_amdgcn_sched_barrier(0);                                           \
    if (act) reg_part<PP>(v4, w4, hr, acc);                                      \
    {                                                                            \
      const int j2 = 4 * ((N) + 1) + 2;                                          \
      const int j3 = (4 * ((N) + 1) + 3 <= 50) ? 4 * ((N) + 1) + 3 : 50;         \
      hr[0] = *reinterpret_cast<const float4*>(hbase + (size_t)j2 * KSTRIDE);    \
      hr[1] = *reinterpret_cast<const float4*>(hbase + (size_t)j2 * KSTRIDE + 4);\
      hr[2] = *reinterpret_cast<const float4*>(hbase + (size_t)j3 * KSTRIDE);    \
      hr[3] = *reinterpret_cast<const float4*>(hbase + (size_t)j3 * KSTRIDE + 4);\
    }                                                                            \
    if (act) lds_part<PP>(v4, w4, woff, (WCOL), hbuf + buf * HCH, off0, off1, acc, lds); \
    asm volatile("s_waitcnt vmcnt(4)" ::: "memory");                             \
    __builtin_amdgcn_s_barrier();                                                \
    buf ^= 1;                                                                    \
  }

#pragma unroll 1
  for (int t = 0; t < 4; ++t) {          // uniform trip count for ALL waves (barriers!)
    const bool act = (t < nblk);
    float4 v4[4][2];
    float4 w4[4][3];
    int    woff[4];
    if (act) {
      const int ibase = (blk0 + t) * 4;
#pragma unroll
      for (int ib = 0; ib < 4; ++ib) {
        const int iv = ibase + ib;                 // <= 51
        const int ic = (iv <= 50) ? iv : 50;
        float4 va = *reinterpret_cast<const float4*>(vbase + (size_t)ic * KSTRIDE);
        float4 vb = *reinterpret_cast<const float4*>(vbase + (size_t)ic * KSTRIDE + 4);
        if (iv > 50) { va = make_float4(0.f, 0.f, 0.f, 0.f); vb = va; }
        v4[ib][0] = va; v4[ib][1] = vb;
        woff[ib] = (ty + ic) * LDS_W;              // row <= 57
        const float4* p = reinterpret_cast<const float4*>(&lds[woff[ib] + lx]);
        w4[ib][0] = p[0]; w4[ib][1] = p[1]; w4[ib][2] = p[2];
      }
    }

#pragma unroll 1
    for (int g = 0; g < 4; ++g) {        // 12 full chunks (N = 3g..3g+2), phase = N mod 3
      const int n0 = 3 * g;
      const int cb = lx + 12 * g + 12;
      STEP(0, n0 + 0, cb + 0);
      STEP(1, n0 + 1, cb + 4);
      STEP(2, n0 + 2, cb + 8);
    }

    // Epilogue chunk 12 (phase 0): j=48,49 from LDS; j=50 = hr[0],hr[1]; j=51 skipped.
    stage(0, buf ^ 1);                   // next round's chunk 0 (dead at t=3, harmless)
    __builtin_amdgcn_sched_barrier(0);
    if (act) fma_jtap<0, 2>(v4, w4, hr[0], hr[1], acc);
    // Prefetch chunk-0 taps {2,3} for the next round (dead at t=3, harmless).
    hr[0] = *reinterpret_cast<const float4*>(hbase + (size_t)2 * KSTRIDE);
    hr[1] = *reinterpret_cast<const float4*>(hbase + (size_t)2 * KSTRIDE + 4);
    hr[2] = *reinterpret_cast<const float4*>(hbase + (size_t)3 * KSTRIDE);
    hr[3] = *reinterpret_cast<const float4*>(hbase + (size_t)3 * KSTRIDE + 4);
    if (act) {
      const float* hb = hbuf + buf * HCH;
      const float4 e0a = *reinterpret_cast<const float4*>(hb + off0);
      const float4 e0b = *reinterpret_cast<const float4*>(hb + off1);
      const float4 e1a = *reinterpret_cast<const float4*>(hb + 512 + off0);
      const float4 e1b = *reinterpret_cast<const float4*>(hb + 512 + off1);
      fma_jtap<0, 0>(v4, w4, e0a, e0b, acc);
      fma_jtap<0, 1>(v4, w4, e1a, e1b, acc);
    }
    asm volatile("s_waitcnt vmcnt(4)" ::: "memory");
    __builtin_amdgcn_s_barrier();
    buf ^= 1;
  }
#undef STEP

  // ---- Reduce the 4 i-split partials (waves 1..3 -> LDS inp region, wave 0 adds & stores)
  __syncthreads();   // full drain (dead DMA + dead hr) + order inp-tile reads before reuse
  if (s > 0) {
    float* p = &lds[((s - 1) * 64 + ty * NTX + tx) * R];
#pragma unroll
    for (int rx = 0; rx < R; ++rx) p[rx] = acc[rx];
  }
  __syncthreads();
  if (s == 0) {
#pragma unroll
    for (int g = 0; g < 3; ++g) {
      const float* p = &lds[(g * 64 + ty * NTX + tx) * R];
#pragma unroll
      for (int rx = 0; rx < R; ++rx) acc[rx] += p[rx];
    }
    float* o = out + (((size_t)(b * NC + c)) * HH + yg) * WW + xg;
    *reinterpret_cast<float4*>(o)     = make_float4(acc[0], acc[1], acc[2], acc[3]);
    *reinterpret_cast<float4*>(o + 4) = make_float4(acc[4], acc[5], acc[6], acc[7]);
  }
}

extern "C" void kernel_launch(void* const* d_in, const int* in_sizes, int n_in,
                              void* d_out, int out_size, void* d_ws, size_t ws_size,
                              hipStream_t stream) {
  const float* inp   = (const float*)d_in[0];
  const float* vert  = (const float*)d_in[1];
  const float* horiz = (const float*)d_in[2];
  float* out = (float*)d_out;

  dim3 grid(WW / TILE_W, HH / TILE_H, NB * NC);   // 4 x 32 x 6 = 768 blocks x 256 threads
  sepconv_kernel<<<grid, NTHREADS, 0, stream>>>(inp, vert, horiz, out);
}

// Round 12
// 144.434 us; speedup vs baseline: 1.1978x; 1.1978x over previous
//
#include <hip/hip_runtime.h>

// Adaptive separable conv (SepConv): out[b,c,y,x] = sum_i sum_j inp[b,c,y+i,x+j]*v[b,i,y,x]*h[b,j,y,x]
// B=2,C=3,H=W=256,K=51. fp32 in/out. No MFMA path (per-pixel weights; no fp32 MFMA on CDNA4).
//
// R12: occupancy via grid. R11 falsified the LDS-BW theory (cut LDS traffic 26% -> worse);
// R7 (73us) is LATENCY-bound at 12 waves/CU, and 12 is a GRID limit (768 blocks = 3.0/CU).
// R10 slope: 12->8 waves cost 12%. So: split the i-range across grid.z (z = half*6+bc,
// 2 halves: taps 0..25 / 26..50). inp tile shrinks to 33 rows -> LDS 31.7KB -> 5 blocks/CU;
// grid 1536 -> ~20 waves/CU resident. Halves write partials to d_ws; a tiny second kernel
// sums into out (+~3us). Cost: +8% h LDS-reads, +12MB inp restage - on idle pipes.
// Keeps R7 exactly: R=8, TILE 64x8, 4-tap h DMA chunks double-buffered (__syncthreads),
// 3-slot zero-mov windows, h row-rotation DMA layout, 1.25 ops/MAC, launch_bounds(256,1).

namespace {
constexpr int KK = 51;
constexpr int NB = 2;
constexpr int NC = 3;
constexpr int HH = 256;
constexpr int WW = 256;
constexpr int IN_H = HH + KK - 1;   // 306
constexpr int IN_W = WW + KK - 1;   // 306

constexpr int TILE_W = 64;          // output cols per block
constexpr int TILE_H = 8;           // output rows per block
constexpr int NTX = 8;              // threads along x (each covers R=8 outputs)
constexpr int R = 8;
constexpr int NTY = 8;
constexpr int NS = 4;               // i-tap split within the half (one range per wave)
constexpr int NTHREADS = NTX * NTY * NS;   // 256
constexpr int HALO_W = TILE_W + KK - 1;    // 114
constexpr int LDS_W = 116;          // 114 valid + 2 slack
constexpr int LDS_H = 33;           // TILE_H-1 + 26 taps/half  (rows ROWBASE..ROWBASE+32)
constexpr int KSTRIDE = HH * WW;    // per-tap stride in v/h (65536)
constexpr int HCH = 4 * TILE_H * TILE_W;   // 2048 floats per 4-tap h chunk buffer
constexpr int OUTN = NB * NC * HH * WW;    // 393216 floats per half-partial
}

__device__ __forceinline__ float fget(const float4 v, int i) {
  return (i == 0) ? v.x : (i == 1) ? v.y : (i == 2) ? v.z : v.w;
}

// One j-tap: t = sum_ib v[ib]*w[ib], acc += h*t. P = window phase, JJ = j within chunk.
template <int P, int JJ>
__device__ __forceinline__ void fma_jtap(const float4 (&v4)[4][2], const float4 (&w4)[4][3],
                                         const float4 ha, const float4 hb, float (&acc)[R]) {
#pragma unroll
  for (int rx = 0; rx < R; ++rx) {
    const int k  = rx + JJ;            // logical window index 0..10
    const int sl = (P + k / 4) % 3;    // physical slot
    const int cp = k & 3;
    const int vh = rx >> 2, vc = rx & 3;
    float tv = fget(v4[0][vh], vc) * fget(w4[0][sl], cp);
    tv = fmaf(fget(v4[1][vh], vc), fget(w4[1][sl], cp), tv);
    tv = fmaf(fget(v4[2][vh], vc), fget(w4[2][sl], cp), tv);
    tv = fmaf(fget(v4[3][vh], vc), fget(w4[3][sl], cp), tv);
    const float hv = (rx < 4) ? fget(ha, vc) : fget(hb, vc);
    acc[rx] = fmaf(hv, tv, acc[rx]);
  }
}

// Full chunk (4 j-taps) at phase P; h from LDS buffer hb (off0/off1 = rotated row offsets);
// then refill the vacated window slot P from the inp tile.
template <int P>
__device__ __forceinline__ void full_chunk(const float4 (&v4)[4][2], float4 (&w4)[4][3],
                                           const int (&woff)[4], int wcol,
                                           const float* hb, int off0, int off1,
                                           float (&acc)[R], const float* smem) {
  const float4 h0a = *reinterpret_cast<const float4*>(hb + off0);
  const float4 h0b = *reinterpret_cast<const float4*>(hb + off1);
  const float4 h1a = *reinterpret_cast<const float4*>(hb + 512 + off0);
  const float4 h1b = *reinterpret_cast<const float4*>(hb + 512 + off1);
  fma_jtap<P, 0>(v4, w4, h0a, h0b, acc);
  const float4 h2a = *reinterpret_cast<const float4*>(hb + 1024 + off0);
  const float4 h2b = *reinterpret_cast<const float4*>(hb + 1024 + off1);
  fma_jtap<P, 1>(v4, w4, h1a, h1b, acc);
  const float4 h3a = *reinterpret_cast<const float4*>(hb + 1536 + off0);
  const float4 h3b = *reinterpret_cast<const float4*>(hb + 1536 + off1);
  fma_jtap<P, 2>(v4, w4, h2a, h2b, acc);
  fma_jtap<P, 3>(v4, w4, h3a, h3b, acc);
#pragma unroll
  for (int ib = 0; ib < 4; ++ib)
    w4[ib][P] = *reinterpret_cast<const float4*>(&smem[woff[ib] + wcol]);
}

__global__ __launch_bounds__(NTHREADS, 1)
void sepconv_kernel(
    const float* __restrict__ inp,
    const float* __restrict__ vert,
    const float* __restrict__ horiz,
    float* __restrict__ ws)
{
  __shared__ float lds[LDS_H * LDS_W];   // 15,312 B (inp tile slice; reused for reduction)
  __shared__ float hbuf[2 * HCH];        // 16,384 B (h double buffer)

  const int tid = threadIdx.x;
  const int tx  = tid & (NTX - 1);
  const int ty  = (tid >> 3) & (NTY - 1);
  const int s   = tid >> 6;                    // wave id: 0..3 (wave-uniform)

  const int x0 = blockIdx.x * TILE_W;
  const int y0 = blockIdx.y * TILE_H;
  const int zz = blockIdx.z;                   // 0..11
  const int bc = zz % (NB * NC);               // 0..5
  const int half = zz / (NB * NC);             // 0..1
  const int b  = bc / NC;
  const int c  = bc % NC;

  const int ROWBASE = half * 26;               // first i-tap of this half
  const int ROWMAX  = half ? 50 : 25;          // last real i-tap of this half

  // ---- Stage input slice: rows y0+ROWBASE .. +32 (clamped), 114 cols (float2).
  {
    const float* src = inp + (((size_t)(b * NC + c)) * IN_H) * IN_W + x0;
    constexpr int total2 = LDS_H * (HALO_W / 2);   // 33*57 = 1881
    for (int e = tid; e < total2; e += NTHREADS) {
      const int col2 = e % (HALO_W / 2);
      const int r    = e / (HALO_W / 2);
      const int gr   = min(y0 + ROWBASE + r, IN_H - 1);   // clamp (only masked taps touch it)
      const float2 v = *reinterpret_cast<const float2*>(src + (size_t)gr * IN_W + col2 * 2);
      float* dst = &lds[r * LDS_W + col2 * 2];
      dst[0] = v.x; dst[1] = v.y;
    }
  }

  // ---- h DMA mapping (4-tap chunks). Physical float4 slot p = r*256+tid:
  // jj=p>>7 (0..3), row=(p&127)>>4, c4=p&15; slot holds global quad q=(c4-row)&15.
  const float* hblk = horiz + (((size_t)b * KK) * HH + y0) * WW + x0;
  int jj_[2], goff_[2], ldso_[2];
#pragma unroll
  for (int r = 0; r < 2; ++r) {
    const int p   = r * 256 + tid;
    const int rem = p & 127;
    const int row = rem >> 4;
    const int c4  = rem & 15;
    const int q   = (c4 - row) & 15;
    jj_[r]   = p >> 7;
    goff_[r] = row * WW + q * 4;
    ldso_[r] = (r * 256 + (tid & ~63)) * 4;    // wave-uniform DMA dest base (floats)
  }
  auto stage = [&](int cc, int bufn) {
#pragma unroll
    for (int r = 0; r < 2; ++r) {
      const int j  = 4 * cc + jj_[r];
      const int jc = (j <= 50) ? j : 50;       // clamp (tap-51 data never read)
      const float* g = hblk + (size_t)jc * KSTRIDE + goff_[r];
      float* l = &hbuf[bufn * HCH + ldso_[r]];
      __builtin_amdgcn_global_load_lds((const __attribute__((address_space(1))) void*)g,
                                       (__attribute__((address_space(3))) void*)l, 16, 0, 0);
    }
  };

  // Prologue: chunk 0 -> buf0. Sync drains inp staging + DMA.
  stage(0, 0);
  __syncthreads();
  int buf = 0, ccn = 1;

  const int lx = tx * R;                 // local LDS col base (32B aligned)
  const int xg = x0 + lx;
  const int yg = y0 + ty;

  // Rotated h read offsets (invariant): row ty, logical quads 2tx, 2tx+1.
  const int off0 = ty * 64 + ((2 * tx + ty) & 15) * 4;
  const int off1 = ty * 64 + ((2 * tx + 1 + ty) & 15) * 4;

  float acc[R];
#pragma unroll
  for (int rx = 0; rx < R; ++rx) acc[rx] = 0.f;

  // Deal 7 BI=4 tap-blocks (28 virtual taps of this half) to 4 waves: 2/2/2/1.
  const int blk0 = (s < 3) ? 2 * s : 6;
  const int nblk = (s < 3) ? 2 : 1;

  const float* vbase = vert + (((size_t)b * KK) * HH + yg) * WW + xg;

#pragma unroll 1
  for (int t = 0; t < 2; ++t) {          // uniform trip count for ALL waves (barriers!)
    const bool act = (t < nblk);
    float4 v4[4][2];
    float4 w4[4][3];
    int    woff[4];
    if (act) {
      const int ibase = ROWBASE + (blk0 + t) * 4;
#pragma unroll
      for (int ib = 0; ib < 4; ++ib) {
        const int iv = ibase + ib;                 // real tap index (may exceed ROWMAX)
        const int ic = (iv <= ROWMAX) ? iv : ROWMAX;
        float4 va = *reinterpret_cast<const float4*>(vbase + (size_t)ic * KSTRIDE);
        float4 vb = *reinterpret_cast<const float4*>(vbase + (size_t)ic * KSTRIDE + 4);
        if (iv > ROWMAX) { va = make_float4(0.f, 0.f, 0.f, 0.f); vb = va; }
        v4[ib][0] = va; v4[ib][1] = vb;
        woff[ib] = (ty + ic - ROWBASE) * LDS_W;    // row <= 32
        const float4* p = reinterpret_cast<const float4*>(&lds[woff[ib] + lx]);
        w4[ib][0] = p[0]; w4[ib][1] = p[1]; w4[ib][2] = p[2];
      }
    }

#pragma unroll 1
    for (int g = 0; g < 4; ++g) {        // 12 full chunks = 4 groups x 3 phases
      const int base = lx + 12 * g + 12;
      stage(ccn, buf ^ 1); ccn = (ccn == 12) ? 0 : ccn + 1;
      if (act) full_chunk<0>(v4, w4, woff, base + 0, hbuf + buf * HCH, off0, off1, acc, lds);
      __syncthreads(); buf ^= 1;
      stage(ccn, buf ^ 1); ccn = (ccn == 12) ? 0 : ccn + 1;
      if (act) full_chunk<1>(v4, w4, woff, base + 4, hbuf + buf * HCH, off0, off1, acc, lds);
      __syncthreads(); buf ^= 1;
      stage(ccn, buf ^ 1); ccn = (ccn == 12) ? 0 : ccn + 1;
      if (act) full_chunk<2>(v4, w4, woff, base + 8, hbuf + buf * HCH, off0, off1, acc, lds);
      __syncthreads(); buf ^= 1;
    }

    // Epilogue chunk (cc=12, phase 0): j = 48,49,50.
    stage(ccn, buf ^ 1); ccn = (ccn == 12) ? 0 : ccn + 1;   // t=1's last stage is dead; harmless
    if (act) {
      const float* hb = hbuf + buf * HCH;
      const float4 e0a = *reinterpret_cast<const float4*>(hb + off0);
      const float4 e0b = *reinterpret_cast<const float4*>(hb + off1);
      const float4 e1a = *reinterpret_cast<const float4*>(hb + 512 + off0);
      const float4 e1b = *reinterpret_cast<const float4*>(hb + 512 + off1);
      const float4 e2a = *reinterpret_cast<const float4*>(hb + 1024 + off0);
      const float4 e2b = *reinterpret_cast<const float4*>(hb + 1024 + off1);
      fma_jtap<0, 0>(v4, w4, e0a, e0b, acc);
      fma_jtap<0, 1>(v4, w4, e1a, e1b, acc);
      fma_jtap<0, 2>(v4, w4, e2a, e2b, acc);
    }
    __syncthreads(); buf ^= 1;
  }

  // ---- Reduce the 4 i-split partials (waves 1..3 -> LDS inp region, wave 0 adds & stores)
  // (trailing __syncthreads above orders all inp-tile reads before the overwrite)
  if (s > 0) {
    float* p = &lds[((s - 1) * 64 + ty * NTX + tx) * R];
#pragma unroll
    for (int rx = 0; rx < R; ++rx) p[rx] = acc[rx];
  }
  __syncthreads();
  if (s == 0) {
#pragma unroll
    for (int g = 0; g < 3; ++g) {
      const float* p = &lds[(g * 64 + ty * NTX + tx) * R];
#pragma unroll
      for (int rx = 0; rx < R; ++rx) acc[rx] += p[rx];
    }
    float* o = ws + (size_t)half * OUTN + (((size_t)(b * NC + c)) * HH + yg) * WW + xg;
    *reinterpret_cast<float4*>(o)     = make_float4(acc[0], acc[1], acc[2], acc[3]);
    *reinterpret_cast<float4*>(o + 4) = make_float4(acc[4], acc[5], acc[6], acc[7]);
  }
}

// Sum the two i-half partials into the output. 98304 float4 elements.
__global__ __launch_bounds__(256)
void sum_halves(const float4* __restrict__ a, const float4* __restrict__ b,
                float4* __restrict__ o)
{
  const int i = blockIdx.x * 256 + threadIdx.x;   // grid sized exactly
  const float4 x = a[i], y = b[i];
  o[i] = make_float4(x.x + y.x, x.y + y.y, x.z + y.z, x.w + y.w);
}

extern "C" void kernel_launch(void* const* d_in, const int* in_sizes, int n_in,
                              void* d_out, int out_size, void* d_ws, size_t ws_size,
                              hipStream_t stream) {
  const float* inp   = (const float*)d_in[0];
  const float* vert  = (const float*)d_in[1];
  const float* horiz = (const float*)d_in[2];
  float* out = (float*)d_out;
  float* ws  = (float*)d_ws;                      // needs 2 * 393216 floats = 3.15 MB

  dim3 grid(WW / TILE_W, HH / TILE_H, 2 * NB * NC);   // 4 x 32 x 12 = 1536 blocks
  sepconv_kernel<<<grid, NTHREADS, 0, stream>>>(inp, vert, horiz, ws);

  const int n4 = OUTN / 4;                        // 98304
  sum_halves<<<n4 / 256, 256, 0, stream>>>(
      (const float4*)ws, (const float4*)(ws + OUTN), (float4*)out);
}